// Round 9
// baseline (186.804 us; speedup 1.0000x reference)
//
#include <hip/hip_runtime.h>

// Conv1d as implicit GEMM on MFMA bf16 — R13.
// out[n,f,t] = sum_{c,k} x[n,c,t+k] * w[f,c,k] + b[f]
// N=32, C=64, W=4096, F=128, WW=64, out_W=4033. Output fp32.
//
// R13 = R12 (112 us) with tap passes MERGED (R11's math + R12's pressure
// discipline):
//  * One 8-stage pass/body: stage ms = 4 MFMA(A[ms],Bt0) + 4 MFMA(A[ms+1],
//    Bt1). 9 A ds_reads/body (was 16: R12's sched_barrier blocked the CSE
//    R11 got implicitly). Rolling 3-slot window, prefetch dist 2 (~230 cyc
//    cover >= 120 LDS latency).
//  * BOTH taps' B loop-carried: Bn0 issued @stage 5, Bn1 @stage 6 (~350-500
//    cyc cover >= L2). Next-body A-seeds (Ac0/Ac1) prefetched @stage 6;
//    re-seeded after the c-half restage (prefetch would be stale).
//  * Arch-reg forced-live ~100 < 128 (acc's 128 live in AGPR half of the
//    unified file) -> no spill; runtime-loop back-edge dam kept.
//  * Unchanged: frag-packed B global->reg (1 MB, L2-resident), barrier-free
//    main loop, c-half xt 25.6 KB, setprio, LDS-transpose epilogue.

#define C_TOT    64
#define F_TOT    128
#define KW       64
#define OUT_W    4033
#define W_IN     4096
#define N_BATCH  32
#define T_BLK    256
#define XROWS    320
#define XSTR     40            // xt row stride (shorts) = 80 B
#define TRS      260           // epilogue transpose row stride (dwords)

typedef __attribute__((ext_vector_type(8))) short  short8;
typedef __attribute__((ext_vector_type(4))) float  floatx4;

__device__ inline unsigned short f32_to_bf16(float f) {
  unsigned int u = __float_as_uint(f);
  u += 0x7FFF + ((u >> 16) & 1);
  return (unsigned short)(u >> 16);
}

// ---- prep: w[f][c][k] fp32 -> frag-packed bf16 (same as R9/R12) ----
// frag id = ((gi*2 + tap)*2 + fh2)*4 + ft ; lane = q*16 + col ; elem e 0..7
//   k = (gi&15) + 32*((gi>>4)&1) + 16*tap
//   f = fh2*64 + ft*16 + col
//   c = (gi>>5)*32 + q*8 + e
// short index = frag*512 + lane*8 + e   (total 1 MB, no padding)
__global__ __launch_bounds__(256) void conv1d_prep(
    const float* __restrict__ w, unsigned short* __restrict__ wsw) {
  int j = blockIdx.x * 256 + threadIdx.x;     // 131072 ushort4 jobs
  if (j < 131072) {
    int e4  = (j & 1) * 4;
    int col = (j >> 1) & 15;
    int q   = (j >> 5) & 3;
    int ft  = (j >> 7) & 3;
    int fh2 = (j >> 9) & 1;
    int tap = (j >> 10) & 1;
    int gi  = j >> 11;
    int k   = (gi & 15) + 32 * ((gi >> 4) & 1) + 16 * tap;
    int f   = fh2 * 64 + ft * 16 + col;
    int c0  = (gi >> 5) * 32 + q * 8 + e4;
    const float* src = w + ((size_t)f * C_TOT + c0) * KW + k;
    ushort4 o;
    o.x = f32_to_bf16(src[0 * KW]);
    o.y = f32_to_bf16(src[1 * KW]);
    o.z = f32_to_bf16(src[2 * KW]);
    o.w = f32_to_bf16(src[3 * KW]);
    *(ushort4*)&wsw[(size_t)j * 4] = o;
  }
}

// ---------------- main GEMM ----------------
__global__ __launch_bounds__(256, 2) void conv1d_mfma(
    const float* __restrict__ x, const unsigned short* __restrict__ wsw,
    const float* __restrict__ b, float* __restrict__ out) {
  __shared__ union SM {
    unsigned short xt[XROWS * XSTR];   // 25.6 KB  x tile bf16 [t][c-half]
    float tr[32 * TRS];                // 33.3 KB  epilogue overlay
  } sm;

  const int tid  = threadIdx.x;
  const int lane = tid & 63;
  const int q    = lane >> 4;    // 0..3
  const int col  = lane & 15;
  const int wv   = tid >> 6;     // 0..3
  const int n    = blockIdx.y;
  const int t0   = blockIdx.x * T_BLK;
  const int fh2  = wv & 1;       // f half (64 f)
  const int th   = wv >> 1;      // t half (128 t)

  const float* xrowb = x + (size_t)n * C_TOT * W_IN;
  // per-thread w pointer: frag(gi,tap,ft) = wp[gi*1024 + tap*512 + ft*64]
  const short8* wp = (const short8*)wsw + fh2 * 256 + lane;

  floatx4 acc[8][4];             // [ms][ft]
#pragma unroll
  for (int ms = 0; ms < 8; ++ms)
#pragma unroll
    for (int ft = 0; ft < 4; ++ft) acc[ms][ft] = (floatx4)0.0f;

  // x stage for one c-half: c-strided dword loads -> ushort4 writes
#define STAGE_X(hc_)                                                           \
  {                                                                            \
    _Pragma("unroll")                                                          \
    for (int r = 0; r < 10; ++r) {                                             \
      int ti = (r % 5) * 64 + (tid & 63);                                      \
      int cl = ((r / 5) * 4 + (tid >> 6)) * 4;                                 \
      int gt = t0 + ti;                                                        \
      const float* src = xrowb + (size_t)((hc_) * 32 + cl) * W_IN + gt;        \
      float4 v = {0.f, 0.f, 0.f, 0.f};                                         \
      if (gt < W_IN) {                                                         \
        v.x = src[0];                                                          \
        v.y = src[W_IN];                                                       \
        v.z = src[2 * W_IN];                                                   \
        v.w = src[3 * W_IN];                                                   \
      }                                                                        \
      ushort4 o;                                                               \
      o.x = f32_to_bf16(v.x); o.y = f32_to_bf16(v.y);                          \
      o.z = f32_to_bf16(v.z); o.w = f32_to_bf16(v.w);                          \
      *(ushort4*)&sm.xt[ti * XSTR + cl] = o;                                   \
    }                                                                          \
  }

  // prologue: stage x c-half 0; preload gi=0 B (both taps) and A seeds
  STAGE_X(0)
  short8 Bt0[4], Bt1[4];
#pragma unroll
  for (int ft = 0; ft < 4; ++ft) {
    Bt0[ft] = wp[ft * 64];
    Bt1[ft] = wp[512 + ft * 64];
  }
  __syncthreads();
  short8 Ac0, Ac1;
  {
    const unsigned short* ap0 = &sm.xt[(128 * th + col) * XSTR + q * 8];
    Ac0 = *(const short8*)&ap0[0];
    Ac1 = *(const short8*)&ap0[1 * 16 * XSTR];
  }

  for (int gi = 0; gi < 64; ++gi) {
    const int k1 = (gi & 15) + 32 * ((gi >> 4) & 1);   // taps (k1, k1+16)
    const unsigned short* ap = &sm.xt[(128 * th + col + k1) * XSTR + q * 8];
    const short8* wpn = (gi < 63) ? wp + 1024 : wp;    // next-body frags

    short8 As[3];
    As[0] = Ac0;                 // A[0] (prefetched last body)
    As[1] = Ac1;                 // A[1]
    short8 Bn0[4], Bn1[4];

    __builtin_amdgcn_s_setprio(1);
#pragma unroll
    for (int ms = 0; ms < 8; ++ms) {
      if (ms < 7)                // A[ms+2] -> slot (ms+2)%3 (dist-2 cover)
        As[(ms + 2) % 3] = *(const short8*)&ap[(ms + 2) * 16 * XSTR];
      if (ms == 5) {             // next-body tap0 B (cover ~3 stages)
#pragma unroll
        for (int ft = 0; ft < 4; ++ft) Bn0[ft] = wpn[ft * 64];
      }
      if (ms == 6) {             // next-body tap1 B + next-body A seeds
#pragma unroll
        for (int ft = 0; ft < 4; ++ft) Bn1[ft] = wpn[512 + ft * 64];
        const int gin = (gi < 63) ? gi + 1 : 63;
        const int k1n = (gin & 15) + 32 * ((gin >> 4) & 1);
        const unsigned short* apn =
            &sm.xt[(128 * th + col + k1n) * XSTR + q * 8];
        Ac0 = *(const short8*)&apn[0];
        Ac1 = *(const short8*)&apn[1 * 16 * XSTR];
      }
#pragma unroll
      for (int ft = 0; ft < 4; ++ft)
        acc[ms][ft] = __builtin_amdgcn_mfma_f32_16x16x32_bf16(
            As[ms % 3], Bt0[ft], acc[ms][ft], 0, 0, 0);
#pragma unroll
      for (int ft = 0; ft < 4; ++ft)
        acc[ms][ft] = __builtin_amdgcn_mfma_f32_16x16x32_bf16(
            As[(ms + 1) % 3], Bt1[ft], acc[ms][ft], 0, 0, 0);
    }
    __builtin_amdgcn_s_setprio(0);

    // carry next-body B (compile-time-indexed moves)
#pragma unroll
    for (int ft = 0; ft < 4; ++ft) {
      Bt0[ft] = Bn0[ft];
      Bt1[ft] = Bn1[ft];
    }
    wp += 1024;

    if (gi == 31) {              // c-half switch (xt readers all done)
      __syncthreads();
      STAGE_X(1)
      __syncthreads();
      // prefetched A seeds crossed the restage -> re-seed from fresh xt
      // (gi=32: k1 = 0)
      const unsigned short* ap32 = &sm.xt[(128 * th + col) * XSTR + q * 8];
      Ac0 = *(const short8*)&ap32[0];
      Ac1 = *(const short8*)&ap32[1 * 16 * XSTR];
    }
  }
  __syncthreads();               // waves may drift: resync before tr overlay

  // ---- epilogue: LDS transpose to [f][t], coalesced float4 stores ----
  // D layout: t_loc = 128*th + 16*ms + 4*q + r, f = 64*fh2 + 16*ft + col
  const int fs_w  = fh2 * 16 + col;     // f-slot for writes (0..31)
  const int fs_r  = tid >> 3;           // f-slot for reads (0..31)
  const int seg   = tid & 7;
  const int f_r   = (fs_r >> 4) * 64 + (fs_r & 15);
  const size_t ob = ((size_t)n * F_TOT) * OUT_W;

#pragma unroll
  for (int j = 0; j < 4; ++j) {         // round j handles ft == j (COMPILE-TIME)
#pragma unroll
    for (int ms = 0; ms < 8; ++ms) {
      float4 vv;
      vv.x = acc[ms][j][0];
      vv.y = acc[ms][j][1];
      vv.z = acc[ms][j][2];
      vv.w = acc[ms][j][3];
      int tl = 128 * th + 16 * ms + 4 * q;
      *(float4*)&sm.tr[fs_w * TRS + tl] = vv;
    }
    __syncthreads();
    const int f = f_r + 16 * j;
    const float bias = b[f];
    const size_t obf = ob + (size_t)f * OUT_W;
#pragma unroll
    for (int j2 = 0; j2 < 8; ++j2) {
      int tl = seg * 4 + 32 * j2;
      float4 vv = *(const float4*)&sm.tr[fs_r * TRS + tl];
      vv.x += bias; vv.y += bias; vv.z += bias; vv.w += bias;
      int t = t0 + tl;
      if (t + 3 < OUT_W) {
        *(float4*)&out[obf + t] = vv;
      } else {
        float e[4] = {vv.x, vv.y, vv.z, vv.w};
#pragma unroll
        for (int u = 0; u < 4; ++u)
          if (t + u < OUT_W) out[obf + t + u] = e[u];
      }
    }
    __syncthreads();
  }
}

extern "C" void kernel_launch(void* const* d_in, const int* in_sizes, int n_in,
                              void* d_out, int out_size, void* d_ws, size_t ws_size,
                              hipStream_t stream) {
  const float* x = (const float*)d_in[0];
  const float* w = (const float*)d_in[1];
  const float* b = (const float*)d_in[2];
  float* out = (float*)d_out;

  unsigned short* wsw = (unsigned short*)d_ws;   // 1 MB frag-packed bf16 w

  conv1d_prep<<<512, 256, 0, stream>>>(w, wsw);

  dim3 grid((OUT_W + T_BLK - 1) / T_BLK, N_BATCH);  // 16 x 32 = 512 blocks
  conv1d_mfma<<<grid, 256, 0, stream>>>(x, wsw, b, out);
}